// Round 12
// baseline (499.821 us; speedup 1.0000x reference)
//
#include <hip/hip_runtime.h>
#include <hip/hip_bf16.h>

#define N_NODES 100000
#define D 128
#define EPT 250000
#define NT 7
#define NSEG (NT * N_NODES)   // 700000
#define TOTE (NT * EPT)       // 1750000
#define ZROW N_NODES          // index of the all-zero row appended to xb

#define SCAN_B 256
#define SCAN_IPT 4
#define SCAN_CHUNK (SCAN_B * SCAN_IPT)                    // 1024
#define SCAN_NBLK ((NSEG + SCAN_CHUNK - 1) / SCAN_CHUNK)  // 684

#define CVX_BLOCKS 12500   // 3,200,000 float4 / 256 (exact)
#define CVW_BLOCKS 512     // 131,072 / 256 (exact)
#define CNT_BLOCKS 977     // ceil(250000/256)

typedef __attribute__((ext_vector_type(8))) short bf16x8;
typedef __attribute__((ext_vector_type(4))) float f32x4;

__device__ inline float b2f(unsigned int u16) {
    union { unsigned int i; float f; } v; v.i = u16 << 16; return v.f;
}
__device__ inline unsigned short f2b(float f) {
    union { float f; unsigned int i; } v; v.f = f;
    unsigned int r = v.i + 0x7fffu + ((v.i >> 16) & 1u);
    return (unsigned short)(r >> 16);
}
__device__ inline unsigned int pack2(float a, float b) {
    return (unsigned int)f2b(a) | ((unsigned int)f2b(b) << 16);
}

struct EPtrs { const int* e[NT]; };

// ---------------- merged prep: convert_x | zero-row | convert_w | count_all ----------------

__global__ __launch_bounds__(256) void prep(const float4* __restrict__ x, uint2* __restrict__ xb,
                                            const float* __restrict__ W, unsigned short* __restrict__ WbT,
                                            EPtrs ep, int* __restrict__ cnt) {
    int b = blockIdx.x, tid = threadIdx.x;
    if (b < CVX_BLOCKS) {
        int i = b * 256 + tid;               // < 3,200,000 exact
        float4 v = x[i];
        xb[i] = make_uint2(pack2(v.x, v.y), pack2(v.z, v.w));
    } else if (b == CVX_BLOCKS) {
        if (tid < 16) ((uint4*)xb)[(size_t)ZROW * 16 + tid] = make_uint4(0u, 0u, 0u, 0u);
    } else if (b < CVX_BLOCKS + 1 + CVW_BLOCKS) {
        int i = (b - CVX_BLOCKS - 1) * 256 + tid;  // < 131072 exact
        int c = i >> 10, tk = i & 1023;
        WbT[i] = f2b(W[tk * 128 + c] * 0.125f);  // fold /8 (exact pow2)
    } else {
        int r = b - CVX_BLOCKS - 1 - CVW_BLOCKS;
        int t = r / CNT_BLOCKS;
        int i = (r % CNT_BLOCKS) * 256 + tid;
        if (i < EPT) atomicAdd(&cnt[t * N_NODES + ep.e[t][EPT + i]], 1);
    }
}

// ---------------- CSR scan ----------------

__global__ void scan_partials(const int* __restrict__ cnt, int* __restrict__ partials) {
    __shared__ int wsum[4];
    int tid = threadIdx.x;
    int base = blockIdx.x * SCAN_CHUNK + tid * SCAN_IPT;
    int s = 0;
#pragma unroll
    for (int j = 0; j < SCAN_IPT; ++j) {
        int idx = base + j;
        if (idx < NSEG) s += cnt[idx];
    }
    for (int off = 32; off > 0; off >>= 1) s += __shfl_down(s, off);
    if ((tid & 63) == 0) wsum[tid >> 6] = s;
    __syncthreads();
    if (tid == 0) partials[blockIdx.x] = wsum[0] + wsum[1] + wsum[2] + wsum[3];
}

// scan_write with inlined prefix over partials; writes cursor only
__global__ void scan_write(const int* __restrict__ cnt, const int* __restrict__ partials,
                           int* __restrict__ cursor) {
    __shared__ int wsumA[4];
    __shared__ int wsum[4];
    __shared__ int basesh;
    int tid = threadIdx.x;
    int lane = tid & 63, wid = tid >> 6;

    int pre = 0;
    for (int j = tid; j < blockIdx.x; j += SCAN_B) pre += partials[j];
    for (int off = 32; off > 0; off >>= 1) pre += __shfl_down(pre, off);
    if (lane == 0) wsumA[wid] = pre;
    __syncthreads();
    if (tid == 0) basesh = wsumA[0] + wsumA[1] + wsumA[2] + wsumA[3];

    int base = blockIdx.x * SCAN_CHUNK + tid * SCAN_IPT;
    int v[SCAN_IPT];
    int tsum = 0;
#pragma unroll
    for (int j = 0; j < SCAN_IPT; ++j) {
        int idx = base + j;
        v[j] = (idx < NSEG) ? cnt[idx] : 0;
        tsum += v[j];
    }
    int inc = tsum;
    for (int d = 1; d < 64; d <<= 1) {
        int o = __shfl_up(inc, d);
        if (lane >= d) inc += o;
    }
    if (lane == 63) wsum[wid] = inc;
    __syncthreads();
    int woff = 0;
    for (int w = 0; w < wid; ++w) woff += wsum[w];
    int exc = woff + inc - tsum + basesh;
#pragma unroll
    for (int j = 0; j < SCAN_IPT; ++j) {
        int idx = base + j;
        if (idx < NSEG) cursor[idx] = exc;
        exc += v[j];
    }
}

__global__ void fill_all(EPtrs ep, int* __restrict__ cursor, int* __restrict__ esrc) {
    int i = blockIdx.x * blockDim.x + threadIdx.x;
    int t = blockIdx.y;
    if (i < EPT) {
        int src = ep.e[t][i];
        int dst = ep.e[t][EPT + i];
        int pos = atomicAdd(&cursor[t * N_NODES + dst], 1);
        esrc[pos] = src;
    }
}

// ---------------- fused aggregate + GEMM (low-VGPR, full-K) ----------------
// block = 1024 threads (16 waves), tile = 32 nodes, LDS 64 KB
// -> 2 blocks/CU = 32 waves/CU (the HW cap).
// Lane mapping: nloc = tid>>5 (node), chunk = tid&31 (8B = 4-bf16 column
// chunk). Register budget engineered under the 64-VGPR occupancy cliff
// (m69: waves/SIMD halve at vgpr=64; R4's VGPR=20 measured 83% occupancy,
// R5-R11's 52-64 all measured ~41%): uint2 gathers (8 in flight = 16 regs),
// sa/sb[4] (8), g[4] (4), single f32x4 GEMM acc (4, not live during gather).
// launch_bounds(1024,9) caps allocation at 56 regs.
// Phase 1: PAIR-gather all 7 types + global -> LDS [32][8 slots x 128] bf16,
// XOR-swizzled. Phase 2: GEMM full K=1024; wave = 16 rows x 16 cols.

__device__ __forceinline__ uint2 ldrow2(const unsigned short* __restrict__ xb, int idx, int chunk) {
    return *(const uint2*)(xb + (size_t)idx * 128 + chunk * 4);
}

__device__ __forceinline__ void accrow2(float (&s)[4], uint2 v) {
    s[0] += b2f(v.x & 0xffffu);  s[1] += b2f(v.x >> 16);
    s[2] += b2f(v.y & 0xffffu);  s[3] += b2f(v.y >> 16);
}

__device__ __forceinline__ void main4(const unsigned short* __restrict__ xb, int4 h, int c,
                                      int chunk, float (&s)[4]) {
    int i0 = (c > 0) ? h.x : ZROW;
    int i1 = (c > 1) ? h.y : ZROW;
    int i2 = (c > 2) ? h.z : ZROW;
    int i3 = (c > 3) ? h.w : ZROW;
    uint2 v0 = ldrow2(xb, i0, chunk);
    uint2 v1 = ldrow2(xb, i1, chunk);
    uint2 v2 = ldrow2(xb, i2, chunk);
    uint2 v3 = ldrow2(xb, i3, chunk);
    accrow2(s, v0); accrow2(s, v1); accrow2(s, v2); accrow2(s, v3);
}

__device__ __forceinline__ void tail4(const unsigned short* __restrict__ xb,
                                      const int* __restrict__ esrc, int start, int c,
                                      int chunk, float (&s)[4]) {
    if (c > 4) {
        int4 h = *(const int4*)(esrc + start + 4);
        int i5 = (c > 5) ? h.y : ZROW;
        int i6 = (c > 6) ? h.z : ZROW;
        int i7 = (c > 7) ? h.w : ZROW;
        uint2 v4 = ldrow2(xb, h.x, chunk);
        uint2 v5 = ldrow2(xb, i5, chunk);
        uint2 v6 = ldrow2(xb, i6, chunk);
        uint2 v7 = ldrow2(xb, i7, chunk);
        accrow2(s, v4); accrow2(s, v5); accrow2(s, v6); accrow2(s, v7);
        for (int j = 8; j < c; ++j) {  // P ~ 0.2%
            uint2 v = ldrow2(xb, esrc[start + j], chunk);
            accrow2(s, v);
        }
    }
}

__global__ __launch_bounds__(1024, 9) void fused_agg_gemm(const unsigned short* __restrict__ xb,
                                                          const int* __restrict__ cursor,
                                                          const int* __restrict__ cnt,
                                                          const int* __restrict__ esrc,
                                                          const unsigned short* __restrict__ WbT,
                                                          float* __restrict__ out) {
    __shared__ char lds[32 * 2048];  // 64 KB: [32 rows][8 slots x 128 bf16], swizzled

    int tid = threadIdx.x;
    int lane = tid & 63;
    int nloc = tid >> 5;       // 0..31
    int chunk = tid & 31;      // 0..31 (8B chunks)
    int tile0 = blockIdx.x * 32;
    int n = tile0 + nloc;

    char* rowp = lds + nloc * 2048;
    int rsw = (nloc & 7) << 4;
    float g[4] = {0.f, 0.f, 0.f, 0.f};
    int ctot = 0;
    float sa[4], sb[4];

#define LOADSEG(T, STV, CTV)                                                  \
    int STV, CTV;                                                             \
    {                                                                         \
        int e_ = cursor[(T) * N_NODES + n];                                   \
        CTV = cnt[(T) * N_NODES + n];                                         \
        STV = e_ - CTV;                                                       \
    }

#define EMIT(CTV, SLOT, S)                                                    \
    {                                                                         \
        int c_ = CTV;                                                         \
        ctot += c_;                                                           \
        float inv_ = 1.0f / (float)(c_ > 0 ? c_ : 1);                         \
        uint2 pk_;                                                            \
        pk_.x = pack2(S[0] * inv_, S[1] * inv_);                              \
        pk_.y = pack2(S[2] * inv_, S[3] * inv_);                              \
        *(uint2*)(rowp + (((SLOT) * 256 + chunk * 8) ^ rsw)) = pk_;           \
        for (int i_ = 0; i_ < 4; ++i_) g[i_] += S[i_];                        \
    }

#define PAIRX(STA, CTA, STB, CTB, SLA, SLB)                                   \
    {                                                                         \
        int4 ha_ = *(const int4*)(esrc + STA);                                \
        int4 hb_ = *(const int4*)(esrc + STB);                                \
        for (int i_ = 0; i_ < 4; ++i_) { sa[i_] = 0.f; sb[i_] = 0.f; }        \
        main4(xb, ha_, CTA, chunk, sa);                                       \
        main4(xb, hb_, CTB, chunk, sb);                                       \
        tail4(xb, esrc, STA, CTA, chunk, sa);                                 \
        tail4(xb, esrc, STB, CTB, chunk, sb);                                 \
        EMIT(CTA, SLA, sa); EMIT(CTB, SLB, sb);                               \
    }

    // ---- phase 1: all 7 types + global -> LDS slots 0-7 ----
    {
        LOADSEG(0, st0, ct0)
        LOADSEG(1, st1, ct1)
        PAIRX(st0, ct0, st1, ct1, 0, 1)
    }
    {
        LOADSEG(2, st2, ct2)
        LOADSEG(3, st3, ct3)
        PAIRX(st2, ct2, st3, ct3, 2, 3)
    }
    {
        LOADSEG(4, st4, ct4)
        LOADSEG(5, st5, ct5)
        PAIRX(st4, ct4, st5, ct5, 4, 5)
    }
    {
        LOADSEG(6, st6, ct6)
        int4 hc_ = *(const int4*)(esrc + st6);
        for (int i_ = 0; i_ < 4; ++i_) sa[i_] = 0.f;
        main4(xb, hc_, ct6, chunk, sa);
        tail4(xb, esrc, st6, ct6, chunk, sa);
        EMIT(ct6, 6, sa)
    }
    {
        float gi = 1.0f / (float)(ctot > 0 ? ctot : 1);
        uint2 pg;
        pg.x = pack2(g[0] * gi, g[1] * gi);
        pg.y = pack2(g[2] * gi, g[3] * gi);
        *(uint2*)(rowp + ((7 * 256 + chunk * 8) ^ rsw)) = pg;
    }

    __syncthreads();

    // ---- phase 2: GEMM [32][1024] @ WbT -> out[32][128] ----
    // 16 waves: rowhalf = wvu&1 (16 rows), colgroup = wvu>>1 (16 cols).
    int wvu = __builtin_amdgcn_readfirstlane(tid >> 6);
    int lr = lane & 15, lk = lane >> 4;
    int rowhalf = wvu & 1, colgroup = wvu >> 1;
    int row = rowhalf * 16 + lr;
    int rx = (lr & 7) << 4;  // row&7 == lr&7

    f32x4 acc = (f32x4){0.f, 0.f, 0.f, 0.f};
    const unsigned short* wb = WbT + (size_t)(colgroup * 16 + lr) * 1024;

#pragma unroll 4
    for (int k0 = 0; k0 < 1024; k0 += 32) {
        int koff = (k0 + lk * 8) * 2;
        bf16x8 fa = *(const bf16x8*)(lds + ((row * 2048 + koff) ^ rx));
        bf16x8 fb = *(const bf16x8*)(wb + k0 + lk * 8);
        acc = __builtin_amdgcn_mfma_f32_16x16x32_bf16(fa, fb, acc, 0, 0, 0);
    }

    int n0 = tile0 + rowhalf * 16 + lk * 4;
    int col = colgroup * 16 + lr;
#pragma unroll
    for (int qq = 0; qq < 4; ++qq)
        out[(size_t)(n0 + qq) * 128 + col] = acc[qq];
}

// ---------------- launch ----------------

extern "C" void kernel_launch(void* const* d_in, const int* in_sizes, int n_in,
                              void* d_out, int out_size, void* d_ws, size_t ws_size,
                              hipStream_t stream) {
    const float* x = (const float*)d_in[0];
    const float* W = (const float*)d_in[1];
    EPtrs ep;
    for (int t = 0; t < NT; ++t) ep.e[t] = (const int*)d_in[2 + t];
    float* out = (float*)d_out;

    char* ws = (char*)d_ws;
    int* cnt            = (int*)(ws + 0);                    // 2,800,000
    int* cursor         = (int*)(ws + 2800000);              // 2,800,000
    int* partials       = (int*)(ws + 5600000);              // 4,096
    unsigned short* WbT = (unsigned short*)(ws + 5604096);   // 262,144
    int* esrc           = (int*)(ws + 5866240);              // 7,000,000 + 256 pad
    unsigned short* xb  = (unsigned short*)(ws + 12866496);  // 25,600,256 (incl. zero row)

    hipMemsetAsync(cnt, 0, NSEG * sizeof(int), stream);

    int prep_blocks = CVX_BLOCKS + 1 + CVW_BLOCKS + CNT_BLOCKS * NT;  // 19852
    prep<<<prep_blocks, 256, 0, stream>>>((const float4*)x, (uint2*)xb, W, WbT, ep, cnt);

    scan_partials<<<SCAN_NBLK, SCAN_B, 0, stream>>>(cnt, partials);
    scan_write<<<SCAN_NBLK, SCAN_B, 0, stream>>>(cnt, partials, cursor);

    dim3 egrid(CNT_BLOCKS, NT);
    fill_all<<<egrid, 256, 0, stream>>>(ep, cursor, esrc);

    int nblocks = N_NODES / 32;  // 3125, exact
    fused_agg_gemm<<<nblocks, 1024, 0, stream>>>(xb, cursor, cnt, esrc, WbT, out);
}

// Round 13
// 376.361 us; speedup vs baseline: 1.3280x; 1.3280x over previous
//
#include <hip/hip_runtime.h>
#include <hip/hip_bf16.h>

#define N_NODES 100000
#define D 128
#define EPT 250000
#define NT 7
#define NSEG (NT * N_NODES)   // 700000
#define TOTE (NT * EPT)       // 1750000
#define ZROW N_NODES          // index of the all-zero row appended to xb

#define SCAN_B 256
#define SCAN_IPT 4
#define SCAN_CHUNK (SCAN_B * SCAN_IPT)                    // 1024
#define SCAN_NBLK ((NSEG + SCAN_CHUNK - 1) / SCAN_CHUNK)  // 684

#define CVX_BLOCKS 12500   // 3,200,000 float4 / 256 (exact)
#define CVW_BLOCKS 512     // 131,072 / 256 (exact)
#define CNT_BLOCKS 977     // ceil(250000/256)

typedef __attribute__((ext_vector_type(8))) short bf16x8;
typedef __attribute__((ext_vector_type(4))) float f32x4;

__device__ inline float b2f(unsigned int u16) {
    union { unsigned int i; float f; } v; v.i = u16 << 16; return v.f;
}
__device__ inline unsigned short f2b(float f) {
    union { float f; unsigned int i; } v; v.f = f;
    unsigned int r = v.i + 0x7fffu + ((v.i >> 16) & 1u);
    return (unsigned short)(r >> 16);
}
__device__ inline unsigned int pack2(float a, float b) {
    return (unsigned int)f2b(a) | ((unsigned int)f2b(b) << 16);
}

struct EPtrs { const int* e[NT]; };

// ---------------- merged prep: convert_x | zero-row | convert_w | count_all ----------------

__global__ __launch_bounds__(256) void prep(const float4* __restrict__ x, uint2* __restrict__ xb,
                                            const float* __restrict__ W, unsigned short* __restrict__ WbT,
                                            EPtrs ep, int* __restrict__ cnt) {
    int b = blockIdx.x, tid = threadIdx.x;
    if (b < CVX_BLOCKS) {
        int i = b * 256 + tid;               // < 3,200,000 exact
        float4 v = x[i];
        xb[i] = make_uint2(pack2(v.x, v.y), pack2(v.z, v.w));
    } else if (b == CVX_BLOCKS) {
        if (tid < 16) ((uint4*)xb)[(size_t)ZROW * 16 + tid] = make_uint4(0u, 0u, 0u, 0u);
    } else if (b < CVX_BLOCKS + 1 + CVW_BLOCKS) {
        int i = (b - CVX_BLOCKS - 1) * 256 + tid;  // < 131072 exact
        int c = i >> 10, tk = i & 1023;
        WbT[i] = f2b(W[tk * 128 + c] * 0.125f);  // fold /8 (exact pow2)
    } else {
        int r = b - CVX_BLOCKS - 1 - CVW_BLOCKS;
        int t = r / CNT_BLOCKS;
        int i = (r % CNT_BLOCKS) * 256 + tid;
        if (i < EPT) atomicAdd(&cnt[t * N_NODES + ep.e[t][EPT + i]], 1);
    }
}

// ---------------- CSR scan ----------------

__global__ void scan_partials(const int* __restrict__ cnt, int* __restrict__ partials) {
    __shared__ int wsum[4];
    int tid = threadIdx.x;
    int base = blockIdx.x * SCAN_CHUNK + tid * SCAN_IPT;
    int s = 0;
#pragma unroll
    for (int j = 0; j < SCAN_IPT; ++j) {
        int idx = base + j;
        if (idx < NSEG) s += cnt[idx];
    }
    for (int off = 32; off > 0; off >>= 1) s += __shfl_down(s, off);
    if ((tid & 63) == 0) wsum[tid >> 6] = s;
    __syncthreads();
    if (tid == 0) partials[blockIdx.x] = wsum[0] + wsum[1] + wsum[2] + wsum[3];
}

// scan_write with inlined prefix over partials; writes cursor only
__global__ void scan_write(const int* __restrict__ cnt, const int* __restrict__ partials,
                           int* __restrict__ cursor) {
    __shared__ int wsumA[4];
    __shared__ int wsum[4];
    __shared__ int basesh;
    int tid = threadIdx.x;
    int lane = tid & 63, wid = tid >> 6;

    int pre = 0;
    for (int j = tid; j < blockIdx.x; j += SCAN_B) pre += partials[j];
    for (int off = 32; off > 0; off >>= 1) pre += __shfl_down(pre, off);
    if (lane == 0) wsumA[wid] = pre;
    __syncthreads();
    if (tid == 0) basesh = wsumA[0] + wsumA[1] + wsumA[2] + wsumA[3];

    int base = blockIdx.x * SCAN_CHUNK + tid * SCAN_IPT;
    int v[SCAN_IPT];
    int tsum = 0;
#pragma unroll
    for (int j = 0; j < SCAN_IPT; ++j) {
        int idx = base + j;
        v[j] = (idx < NSEG) ? cnt[idx] : 0;
        tsum += v[j];
    }
    int inc = tsum;
    for (int d = 1; d < 64; d <<= 1) {
        int o = __shfl_up(inc, d);
        if (lane >= d) inc += o;
    }
    if (lane == 63) wsum[wid] = inc;
    __syncthreads();
    int woff = 0;
    for (int w = 0; w < wid; ++w) woff += wsum[w];
    int exc = woff + inc - tsum + basesh;
#pragma unroll
    for (int j = 0; j < SCAN_IPT; ++j) {
        int idx = base + j;
        if (idx < NSEG) cursor[idx] = exc;
        exc += v[j];
    }
}

__global__ void fill_all(EPtrs ep, int* __restrict__ cursor, int* __restrict__ esrc) {
    int i = blockIdx.x * blockDim.x + threadIdx.x;
    int t = blockIdx.y;
    if (i < EPT) {
        int src = ep.e[t][i];
        int dst = ep.e[t][EPT + i];
        int pos = atomicAdd(&cursor[t * N_NODES + dst], 1);
        esrc[pos] = src;
    }
}

// ---------------- fused aggregate + GEMM (K-split, full head preload) ----------------
// block = 512 threads (8 waves), tile = 32 nodes, LDS 32 KB.
// R11's structure, but ALL 7 segment descriptors (14 loads) and then ALL 7
// int4 edge-list heads issue at kernel entry — two parallel memory hops
// instead of a 3-hop chain per PAIR group. After that every PAIR's 8 main
// gathers can issue immediately (compiler pipelines pair n+1's gathers under
// pair n's accumulation: no remaining address dependencies).
//   1a: gather types 0-3 -> LDS slots 0-3      | barrier
//   2a: GEMM k=0..511 -> acc                   | barrier
//   1b: gather types 4-6 + global -> slots 0-3 | barrier
//   2b: GEMM k=512..1023 -> out
// launch_bounds(512,4): 128-reg cap; est. peak pressure ~108 (no spill).

__device__ __forceinline__ uint4 ldrow(const unsigned short* __restrict__ xb, int idx, int chunk) {
    return *(const uint4*)(xb + (size_t)idx * 128 + chunk * 8);
}

__device__ __forceinline__ void accrow(float (&s)[8], uint4 v) {
    s[0] += b2f(v.x & 0xffffu);  s[1] += b2f(v.x >> 16);
    s[2] += b2f(v.y & 0xffffu);  s[3] += b2f(v.y >> 16);
    s[4] += b2f(v.z & 0xffffu);  s[5] += b2f(v.z >> 16);
    s[6] += b2f(v.w & 0xffffu);  s[7] += b2f(v.w >> 16);
}

__device__ __forceinline__ void main4(const unsigned short* __restrict__ xb, int4 h, int c,
                                      int chunk, float (&s)[8]) {
    int i0 = (c > 0) ? h.x : ZROW;
    int i1 = (c > 1) ? h.y : ZROW;
    int i2 = (c > 2) ? h.z : ZROW;
    int i3 = (c > 3) ? h.w : ZROW;
    uint4 v0 = ldrow(xb, i0, chunk);
    uint4 v1 = ldrow(xb, i1, chunk);
    uint4 v2 = ldrow(xb, i2, chunk);
    uint4 v3 = ldrow(xb, i3, chunk);
    accrow(s, v0); accrow(s, v1); accrow(s, v2); accrow(s, v3);
}

__device__ __forceinline__ void tail4(const unsigned short* __restrict__ xb,
                                      const int* __restrict__ esrc, int start, int c,
                                      int chunk, float (&s)[8]) {
    if (c > 4) {
        int4 h = *(const int4*)(esrc + start + 4);
        int i5 = (c > 5) ? h.y : ZROW;
        int i6 = (c > 6) ? h.z : ZROW;
        int i7 = (c > 7) ? h.w : ZROW;
        uint4 v4 = ldrow(xb, h.x, chunk);
        uint4 v5 = ldrow(xb, i5, chunk);
        uint4 v6 = ldrow(xb, i6, chunk);
        uint4 v7 = ldrow(xb, i7, chunk);
        accrow(s, v4); accrow(s, v5); accrow(s, v6); accrow(s, v7);
        for (int j = 8; j < c; ++j) {  // P ~ 0.2%
            uint4 v = ldrow(xb, esrc[start + j], chunk);
            accrow(s, v);
        }
    }
}

__global__ __launch_bounds__(512, 4) void fused_agg_gemm(const unsigned short* __restrict__ xb,
                                                         const int* __restrict__ cursor,
                                                         const int* __restrict__ cnt,
                                                         const int* __restrict__ esrc,
                                                         const unsigned short* __restrict__ WbT,
                                                         float* __restrict__ out) {
    __shared__ char lds[32 * 1024];  // 32 KB: [32 rows][512 bf16] (one K-half), swizzled

    int tid = threadIdx.x;
    int lane = tid & 63;
    int nloc = tid >> 4;       // 0..31
    int chunk = tid & 15;      // 0..15
    int tile0 = blockIdx.x * 32;
    int n = tile0 + nloc;

    char* rowp = lds + nloc * 1024;
    int rsw = (nloc & 7) << 4;
    float g[8] = {0.f, 0.f, 0.f, 0.f, 0.f, 0.f, 0.f, 0.f};
    int ctot = 0;
    float sa[8], sb[8];

#define LOADSEG(T, STV, CTV)                                                  \
    int STV, CTV;                                                             \
    {                                                                         \
        int e_ = cursor[(T) * N_NODES + n];                                   \
        CTV = cnt[(T) * N_NODES + n];                                         \
        STV = e_ - CTV;                                                       \
    }

#define EMIT(CTV, SLOT, S)                                                    \
    {                                                                         \
        int c_ = CTV;                                                         \
        ctot += c_;                                                           \
        float inv_ = 1.0f / (float)(c_ > 0 ? c_ : 1);                         \
        uint4 pk_;                                                            \
        pk_.x = pack2(S[0] * inv_, S[1] * inv_);                              \
        pk_.y = pack2(S[2] * inv_, S[3] * inv_);                              \
        pk_.z = pack2(S[4] * inv_, S[5] * inv_);                              \
        pk_.w = pack2(S[6] * inv_, S[7] * inv_);                              \
        *(uint4*)(rowp + (((SLOT) * 256 + chunk * 16) ^ rsw)) = pk_;          \
        for (int i_ = 0; i_ < 8; ++i_) g[i_] += S[i_];                        \
    }

// PAIR with preloaded heads HA/HB: gathers issue with no address dependency.
#define PAIRH(HA, STA, CTA, HB, STB, CTB, SLA, SLB)                           \
    {                                                                         \
        for (int i_ = 0; i_ < 8; ++i_) { sa[i_] = 0.f; sb[i_] = 0.f; }        \
        main4(xb, HA, CTA, chunk, sa);                                        \
        main4(xb, HB, CTB, chunk, sb);                                        \
        tail4(xb, esrc, STA, CTA, chunk, sa);                                 \
        tail4(xb, esrc, STB, CTB, chunk, sb);                                 \
        EMIT(CTA, SLA, sa); EMIT(CTB, SLB, sb);                               \
    }

    // ---- all 7 descriptors in parallel (hop 1) ----
    LOADSEG(0, st0, ct0)
    LOADSEG(1, st1, ct1)
    LOADSEG(2, st2, ct2)
    LOADSEG(3, st3, ct3)
    LOADSEG(4, st4, ct4)
    LOADSEG(5, st5, ct5)
    LOADSEG(6, st6, ct6)
    // ---- all 7 heads in parallel (hop 2) ----
    int4 h0 = *(const int4*)(esrc + st0);
    int4 h1 = *(const int4*)(esrc + st1);
    int4 h2 = *(const int4*)(esrc + st2);
    int4 h3 = *(const int4*)(esrc + st3);
    int4 h4 = *(const int4*)(esrc + st4);
    int4 h5 = *(const int4*)(esrc + st5);
    int4 h6 = *(const int4*)(esrc + st6);

    // ---- phase 1a: types 0-3 -> LDS slots 0-3 ----
    PAIRH(h0, st0, ct0, h1, st1, ct1, 0, 1)
    PAIRH(h2, st2, ct2, h3, st3, ct3, 2, 3)

    __syncthreads();

    // ---- phase 2a: GEMM k = 0..511 ----
    int wvu = __builtin_amdgcn_readfirstlane(tid >> 6);
    int lr = lane & 15, lk = lane >> 4;
    f32x4 acc0 = (f32x4){0.f, 0.f, 0.f, 0.f};
    f32x4 acc1 = (f32x4){0.f, 0.f, 0.f, 0.f};
    const unsigned short* wb = WbT + (size_t)(wvu * 16 + lr) * 1024;
    int rx = (lr & 7) << 4;  // rows r and r+16 share (r&7) -> same XOR

#pragma unroll 4
    for (int k0 = 0; k0 < 512; k0 += 32) {
        int koff = (k0 + lk * 8) * 2;
        bf16x8 fa0 = *(const bf16x8*)(lds + ((lr * 1024 + koff) ^ rx));
        bf16x8 fa1 = *(const bf16x8*)(lds + (((lr + 16) * 1024 + koff) ^ rx));
        bf16x8 fb = *(const bf16x8*)(wb + k0 + lk * 8);
        acc0 = __builtin_amdgcn_mfma_f32_16x16x32_bf16(fa0, fb, acc0, 0, 0, 0);
        acc1 = __builtin_amdgcn_mfma_f32_16x16x32_bf16(fa1, fb, acc1, 0, 0, 0);
    }

    __syncthreads();

    // ---- phase 1b: types 4-6 + global -> LDS slots 0-3 ----
    PAIRH(h4, st4, ct4, h5, st5, ct5, 0, 1)
    {
        for (int i_ = 0; i_ < 8; ++i_) sa[i_] = 0.f;
        main4(xb, h6, ct6, chunk, sa);
        tail4(xb, esrc, st6, ct6, chunk, sa);
        EMIT(ct6, 2, sa)
    }
    {
        float gi = 1.0f / (float)(ctot > 0 ? ctot : 1);
        uint4 pg;
        pg.x = pack2(g[0] * gi, g[1] * gi);
        pg.y = pack2(g[2] * gi, g[3] * gi);
        pg.z = pack2(g[4] * gi, g[5] * gi);
        pg.w = pack2(g[6] * gi, g[7] * gi);
        *(uint4*)(rowp + ((3 * 256 + chunk * 16) ^ rsw)) = pg;
    }

    __syncthreads();

    // ---- phase 2b: GEMM k = 512..1023, then store ----
#pragma unroll 4
    for (int k0 = 0; k0 < 512; k0 += 32) {
        int koff = (k0 + lk * 8) * 2;
        bf16x8 fa0 = *(const bf16x8*)(lds + ((lr * 1024 + koff) ^ rx));
        bf16x8 fa1 = *(const bf16x8*)(lds + (((lr + 16) * 1024 + koff) ^ rx));
        bf16x8 fb = *(const bf16x8*)(wb + 512 + k0 + lk * 8);
        acc0 = __builtin_amdgcn_mfma_f32_16x16x32_bf16(fa0, fb, acc0, 0, 0, 0);
        acc1 = __builtin_amdgcn_mfma_f32_16x16x32_bf16(fa1, fb, acc1, 0, 0, 0);
    }

    int col = wvu * 16 + lr;
    int n0 = tile0 + lk * 4;
#pragma unroll
    for (int qq = 0; qq < 4; ++qq) {
        out[(size_t)(n0 + qq) * 128 + col] = acc0[qq];
        out[(size_t)(n0 + 16 + qq) * 128 + col] = acc1[qq];
    }
}

// ---------------- launch ----------------

extern "C" void kernel_launch(void* const* d_in, const int* in_sizes, int n_in,
                              void* d_out, int out_size, void* d_ws, size_t ws_size,
                              hipStream_t stream) {
    const float* x = (const float*)d_in[0];
    const float* W = (const float*)d_in[1];
    EPtrs ep;
    for (int t = 0; t < NT; ++t) ep.e[t] = (const int*)d_in[2 + t];
    float* out = (float*)d_out;

    char* ws = (char*)d_ws;
    int* cnt            = (int*)(ws + 0);                    // 2,800,000
    int* cursor         = (int*)(ws + 2800000);              // 2,800,000
    int* partials       = (int*)(ws + 5600000);              // 4,096
    unsigned short* WbT = (unsigned short*)(ws + 5604096);   // 262,144
    int* esrc           = (int*)(ws + 5866240);              // 7,000,000 + 256 pad
    unsigned short* xb  = (unsigned short*)(ws + 12866496);  // 25,600,256 (incl. zero row)

    hipMemsetAsync(cnt, 0, NSEG * sizeof(int), stream);

    int prep_blocks = CVX_BLOCKS + 1 + CVW_BLOCKS + CNT_BLOCKS * NT;  // 19852
    prep<<<prep_blocks, 256, 0, stream>>>((const float4*)x, (uint2*)xb, W, WbT, ep, cnt);

    scan_partials<<<SCAN_NBLK, SCAN_B, 0, stream>>>(cnt, partials);
    scan_write<<<SCAN_NBLK, SCAN_B, 0, stream>>>(cnt, partials, cursor);

    dim3 egrid(CNT_BLOCKS, NT);
    fill_all<<<egrid, 256, 0, stream>>>(ep, cursor, esrc);

    int nblocks = N_NODES / 32;  // 3125, exact
    fused_agg_gemm<<<nblocks, 512, 0, stream>>>(xb, cursor, cnt, esrc, WbT, out);
}